// Round 1
// baseline (109.393 us; speedup 1.0000x reference)
//
#include <hip/hip_runtime.h>
#include <hip/hip_bf16.h>

typedef __attribute__((ext_vector_type(8))) short short8;
typedef __attribute__((ext_vector_type(4))) float float4v;
typedef __attribute__((ext_vector_type(16))) float float16v;

// Workspace layout (bytes):
//   xTg  bf16 [16 b][32 g][34 h][34 w][8 c]             : 9,469,952
//   Wg   bf16 [9 s][4 pair][4 nq][8 g][64 n][8 c]       : 1,179,648
//   biasout f32 [256]                                   : 1,024
#define XT_BYTES (16*32*34*34*8*2)
#define WG_BYTES (9*4*4*8*64*8*2)

// ---------------------------------------------------------------------------
// k_prep: fused producer. (unchanged from R12)
// ---------------------------------------------------------------------------
__global__ __launch_bounds__(256) void k_prep(const float* __restrict__ x,
                                              const float* __restrict__ tw1,
                                              const float* __restrict__ tw2,
                                              const float* __restrict__ bias,
                                              __hip_bfloat16* __restrict__ xTg,
                                              __hip_bfloat16* __restrict__ Wg,
                                              float* __restrict__ biasout) {
  __shared__ __align__(16) char smem[256 * 33 * 4];   // 33792 B, both phases fit
  int blk = blockIdx.x;
  int tid = threadIdx.x;

  if (blk < 512) {   // ---------------- transpose ----------------
    float* tile = (float*)smem;
    char* xTB = (char*)xTg;
    int h = blk & 31, b = blk >> 5;
    {
      int w4 = (tid & 7) * 4, c0 = tid >> 3;
#pragma unroll
      for (int j = 0; j < 8; ++j) {
        int ci = c0 + 32 * j;
        float4 v = *(const float4*)&x[((b * 256 + ci) * 32 + h) * 32 + w4];
        *(float4*)&tile[ci * 33 + w4] = v;
      }
    }
    __syncthreads();
    {
      int g0 = tid >> 5, w = tid & 31;
#pragma unroll
      for (int gi = 0; gi < 4; ++gi) {
        int g = gi * 8 + g0;
        union { short8 s; __hip_bfloat16 hv[8]; } pk;
#pragma unroll
        for (int cc = 0; cc < 8; ++cc)
          pk.hv[cc] = __float2bfloat16(tile[(g * 8 + cc) * 33 + w]);
        *(short8*)(xTB + ((((b * 32 + g) * 34 + h + 1) * 34) + (w + 1)) * 16) = pk.s;
      }
    }
    if (h < 2) {  // h==0 -> row 0 + col 0 ; h==1 -> row 33 + col 33 (all g)
      uint4 z4 = {0u, 0u, 0u, 0u};
      int edge = h * 33;
      for (int i = tid; i < 32 * 34; i += 256) {
        int g = i / 34, w = i - g * 34;
        *(uint4*)(xTB + ((((b * 32 + g) * 34 + edge) * 34) + w) * 16) = z4;
      }
      for (int i = tid; i < 32 * 32; i += 256) {
        int g = i >> 5, hh = 1 + (i & 31);
        *(uint4*)(xTB + ((((b * 32 + g) * 34 + hh) * 34) + edge) * 16) = z4;
      }
    }
    return;
  }

  // ---------------- build_w ----------------
  int wblk = blk - 512;
  if (wblk == 144) {
    if (tid < 256) {
      float a = 0.f;
#pragma unroll
      for (int s = 0; s < 9; ++s) a += bias[s * 256 + tid];
      biasout[tid] = a * (1.f / 9.f);
    }
    return;
  }
  float* mat = (float*)smem;              // 256*17*4 = 17408 B
  float* tws = (float*)(smem + 17408);    // 2*255*4*4 = 8160 B
  int sidx = wblk >> 4;
  int colbase = (wblk & 15) * 16;

  for (int i = tid; i < 255 * 4; i += 256) {
    tws[i]           = tw1[sidx * 255 * 4 + i];
    tws[255 * 4 + i] = tw2[sidx * 255 * 4 + i];
  }
  {
    int r = tid;
#pragma unroll
    for (int c = 0; c < 16; ++c) mat[r * 17 + c] = (r == colbase + c) ? 1.f : 0.f;
  }

  int c  = tid & 15;
  int pg = tid >> 4;
  for (int ph = 0; ph < 2; ++ph) {
    for (int si = 0; si < 8; ++si) {
      int lg = ph ? si : (7 - si);
      int st = 1 << lg;
      __syncthreads();
      float x0[8], x1[8], t0[8], t1[8], t2[8], t3[8];
#pragma unroll
      for (int i = 0; i < 8; ++i) {
        int qp = pg * 8 + i;
        int li = qp & (st - 1);
        int gi = qp >> lg;
        int p0 = (gi << (lg + 1)) | li;
        int p1 = p0 + st;
        float4 tv = *(const float4*)&tws[(ph * 255 + st - 1 + li) * 4];
        t0[i] = tv.x; t1[i] = tv.y; t2[i] = tv.z; t3[i] = tv.w;
        x0[i] = mat[p0 * 17 + c];
        x1[i] = mat[p1 * 17 + c];
      }
#pragma unroll
      for (int i = 0; i < 8; ++i) {
        int qp = pg * 8 + i;
        int li = qp & (st - 1);
        int gi = qp >> lg;
        int p0 = (gi << (lg + 1)) | li;
        int p1 = p0 + st;
        mat[p0 * 17 + c] = t0[i] * x0[i] + t1[i] * x1[i];
        mat[p1 * 17 + c] = t2[i] * x0[i] + t3[i] * x1[i];
      }
    }
  }
  __syncthreads();

  for (int idx = tid; idx < 256 * 16; idx += 256) {
    int r = idx >> 4, cc = idx & 15;
    int cg = colbase + cc;
    int pr = cg >> 6, g = (cg >> 3) & 7, c8 = cg & 7;
    int nq = r >> 6, nl = r & 63;
    int o = ((((sidx * 4 + pr) * 4 + nq) * 8 + g) * 64 + nl) * 8 + c8;
    Wg[o] = __float2bfloat16(mat[r * 17 + cc] * (1.f / 9.f));
  }
}

// ---------------------------------------------------------------------------
// k_gemm R13: async-pipelined K-loop. Same math/order/epilogue as R12; the
// operand path is restructured for latency hiding:
//   * A (Wg slabs): 3-slot per-wave LDS ring filled by global_load_lds
//     (lane-mailbox: per-lane global src, LDS dst = base + lane*16; the
//     ds_read_b128 at +lane*16 returns exactly what the old direct load got).
//     Stage issued 3-4 bodies ahead of its MFMA use -> ~450 cyc of cover
//     with ZERO VGPR cost for in-flight data.
//   * B (xTg rows): unchanged addressing, but loaded one body ahead into a
//     parity register ring, so MFMAs never wait on a same-body load.
//   * Counted vmcnt (12/10/8 -- derived from guaranteed-issued-after counts,
//     conservative under any intra-body reorder), never drained to 0 in the
//     main loop. lgkmcnt(0)+sched_barrier before each ring overwrite
//     (write-after-read hazard on the slot just consumed).
// LDS ring = 4 waves * 3 slots * 2 KB = 24 KB, inside the existing 32 KB
// block -> still 2 blocks/CU. Barrier-free loop preserved.
// ---------------------------------------------------------------------------

__device__ __forceinline__ void gload16(const char* g, char* l) {
  __builtin_amdgcn_global_load_lds(
      (const __attribute__((address_space(1))) void*)g,
      (__attribute__((address_space(3))) void*)l, 16, 0, 0);
}

#define VMC4  asm volatile("s_waitcnt vmcnt(4)"  ::: "memory")
#define VMC8  asm volatile("s_waitcnt vmcnt(8)"  ::: "memory")
#define VMC10 asm volatile("s_waitcnt vmcnt(10)" ::: "memory")
#define VMC12 asm volatile("s_waitcnt vmcnt(12)" ::: "memory")
#define LGKM0 asm volatile("s_waitcnt lgkmcnt(0)" ::: "memory")
#define SCHEDB __builtin_amdgcn_sched_barrier(0)

// A-stage: 2 KB (a0 | a1) into ring slot SLOT.
#define STGA(GA, SLOT)                                                        \
  { char* sd_ = ring + (SLOT) * 2048;                                         \
    gload16((GA), sd_); gload16((GA) + 512, sd_ + 1024); }

// A-read: slot -> parity regs (ds_read_b128 x2, conflict-free mailbox).
#define RD2(PAR, SLOT)                                                        \
  { const char* sp_ = ring + (SLOT) * 2048 + lane * 16;                       \
    rg[PAR][0] = *(const short8*)(sp_);                                       \
    rg[PAR][1] = *(const short8*)(sp_ + 1024); }

// B-read: 4 rows direct global -> parity regs (same addresses as R12).
#define LDB4(PAR, GB)                                                         \
  { const char* gb_ = (GB);                                                   \
    rb[PAR][0] = *(const short8*)(gb_);                                       \
    rb[PAR][1] = *(const short8*)(gb_ + 544);                                 \
    rb[PAR][2] = *(const short8*)(gb_ + 1088);                                \
    rb[PAR][3] = *(const short8*)(gb_ + 1632); }

#define MFMA8(PAR)                                                            \
  { acc[0][0] = __builtin_amdgcn_mfma_f32_32x32x16_bf16(rg[PAR][0], rb[PAR][0], acc[0][0], 0, 0, 0); \
    acc[0][1] = __builtin_amdgcn_mfma_f32_32x32x16_bf16(rg[PAR][0], rb[PAR][1], acc[0][1], 0, 0, 0); \
    acc[0][2] = __builtin_amdgcn_mfma_f32_32x32x16_bf16(rg[PAR][0], rb[PAR][2], acc[0][2], 0, 0, 0); \
    acc[0][3] = __builtin_amdgcn_mfma_f32_32x32x16_bf16(rg[PAR][0], rb[PAR][3], acc[0][3], 0, 0, 0); \
    acc[1][0] = __builtin_amdgcn_mfma_f32_32x32x16_bf16(rg[PAR][1], rb[PAR][0], acc[1][0], 0, 0, 0); \
    acc[1][1] = __builtin_amdgcn_mfma_f32_32x32x16_bf16(rg[PAR][1], rb[PAR][1], acc[1][1], 0, 0, 0); \
    acc[1][2] = __builtin_amdgcn_mfma_f32_32x32x16_bf16(rg[PAR][1], rb[PAR][2], acc[1][2], 0, 0, 0); \
    acc[1][3] = __builtin_amdgcn_mfma_f32_32x32x16_bf16(rg[PAR][1], rb[PAR][3], acc[1][3], 0, 0, 0); }

// Body K (0..17), runtime p in {0,2}; global iter i = p*9 + K.
// 1. counted-vmcnt wait so stage_{i+1} (issued 3-4 bodies ago) is complete.
// 2. read A_{i+1} from its slot + load B_{i+1} direct (parity regs).
// 3. MFMAs for iter i on last body's regs.
// 4. lgkm(0)+sched_barrier (slot read complete), then stage A_{i+4} into the
//    slot just freed ((K+4)%3 == (K+1)%3).
#define UBODY(K, PP)                                                          \
  {                                                                           \
    if ((K) == 0 && !(PP)) { VMC8; }                                          \
    else if ((K) == 15 && (PP)) { VMC10; }                                    \
    else if ((K) == 16 && (PP)) { VMC8; }                                     \
    else if (!((K) == 17 && (PP))) { VMC12; }                                 \
    if (!((K) == 17 && (PP))) {                                               \
      RD2((((K) + 1) & 1), (((K) + 1) % 3));                                  \
      LDB4((((K) + 1) & 1),                                                   \
           gB0 + (((K) + 1) / 9) * 147968 + ((((K) + 1) % 9) / 3) * 544 +     \
               ((((K) + 1) % 9) % 3) * 16);                                   \
    }                                                                         \
    MFMA8(((K) & 1));                                                         \
    if (!((PP) && (K) >= 14)) {                                               \
      LGKM0; SCHEDB;                                                          \
      STGA(gA0 + (((K) + 4) / 9) * 32768 + (((K) + 4) % 9) * 131072,          \
           (((K) + 1) % 3));                                                  \
    }                                                                         \
  }

__global__ __launch_bounds__(256, 2) void k_gemm(const __hip_bfloat16* __restrict__ xTg,
                                                 const __hip_bfloat16* __restrict__ Wg,
                                                 const float* __restrict__ biasout,
                                                 float* __restrict__ out) {
  __shared__ __align__(128) char lds[32768];
  const char* WgB = (const char*)Wg;
  const char* xTB = (const char*)xTg;

  int blk = blockIdx.x;
  int nq = blk & 3;
  int pt = (blk >> 2) & 7;
  int b  = blk >> 5;
  int h0 = pt * 4;                // output rows h0..h0+3

  int tid  = threadIdx.x;
  int lane = tid & 63;
  int wk   = tid >> 6;            // wave = k-quarter 0..3
  int half = lane >> 5;
  int l31  = lane & 31;

  float16v acc[2][4];             // [mt][p2]
#pragma unroll
  for (int mt = 0; mt < 2; ++mt)
#pragma unroll
    for (int p2 = 0; p2 < 4; ++p2)
#pragma unroll
      for (int e = 0; e < 16; ++e) acc[mt][p2][e] = 0.f;

  // Per-lane global bases (identical addressing to R12's direct loads).
  // A: addr(i) = gAb + p''*32768 + s*131072 (+512 for rows 32..63).
  const char* gAb = WgB + nq * 8192 + ((2 * wk + half) * 64 + l31) * 16;
  // B: addr(i,row) = gBb + p''*147968 + si*544 + sj*16 + row*544.
  const char* gBb = xTB + (((b * 32 + 2 * wk + half) * 34 + h0) * 34 + l31) * 16;

  char* ring = lds + wk * 6144;   // 3 slots x 2 KB per wave

  short8 rg[2][2];                // A parity regs (a0, a1)
  short8 rb[2][4];                // B parity regs (rows 0..3)

  // Prologue: stage iters 0..2, read iter 0 (A+B), stage iter 3.
  STGA(gAb, 0);                   // i=0 (s=0)
  STGA(gAb + 131072, 1);          // i=1
  STGA(gAb + 262144, 2);          // i=2
  VMC4;                           // stage_0 complete (stages 1,2 in flight)
  RD2(0, 0);
  LDB4(0, gBb);                   // iter 0: si=0, sj=0
  LGKM0; SCHEDB;
  STGA(gAb + 3 * 131072, 0);      // i=3 -> slot 0 (just consumed)

  for (int p = 0; p <= 2; p += 2) {
    const int pp = p;             // 0 for first 18 iters, nonzero for last 18
    const char* gA0 = gAb + p * 32768;
    const char* gB0 = gBb + p * 147968;
    UBODY(0, pp)  UBODY(1, pp)  UBODY(2, pp)  UBODY(3, pp)  UBODY(4, pp)
    UBODY(5, pp)  UBODY(6, pp)  UBODY(7, pp)  UBODY(8, pp)  UBODY(9, pp)
    UBODY(10, pp) UBODY(11, pp) UBODY(12, pp) UBODY(13, pp) UBODY(14, pp)
    UBODY(15, pp) UBODY(16, pp) UBODY(17, pp)
  }

  // k-quarter reduction (unchanged). Conflict-free: slot*4096 + lane*16.
  auto st16 = [&](int slot, const float16v& v) {
    char* base = lds + slot * 4096 + lane * 16;
    *(float4v*)(base)        = (float4v){v[0],  v[1],  v[2],  v[3]};
    *(float4v*)(base + 1024) = (float4v){v[4],  v[5],  v[6],  v[7]};
    *(float4v*)(base + 2048) = (float4v){v[8],  v[9],  v[10], v[11]};
    *(float4v*)(base + 3072) = (float4v){v[12], v[13], v[14], v[15]};
  };
  auto ld16add = [&](int slot, float16v& v) {
    const char* base = lds + slot * 4096 + lane * 16;
    float4v t0 = *(const float4v*)(base);
    float4v t1 = *(const float4v*)(base + 1024);
    float4v t2 = *(const float4v*)(base + 2048);
    float4v t3 = *(const float4v*)(base + 3072);
    v[0] += t0[0]; v[1] += t0[1]; v[2]  += t0[2]; v[3]  += t0[3];
    v[4] += t1[0]; v[5] += t1[1]; v[6]  += t1[2]; v[7]  += t1[3];
    v[8] += t2[0]; v[9] += t2[1]; v[10] += t2[2]; v[11] += t2[3];
    v[12] += t3[0]; v[13] += t3[1]; v[14] += t3[2]; v[15] += t3[3];
  };

  __syncthreads();
  if (wk >= 2) {
#pragma unroll
    for (int p2 = 0; p2 < 4; ++p2) st16((wk - 2) * 4 + p2, acc[0][p2]);
  }
  __syncthreads();
  if (wk < 2) {
#pragma unroll
    for (int p2 = 0; p2 < 4; ++p2) ld16add(wk * 4 + p2, acc[0][p2]);
  }
  __syncthreads();
  if (wk >= 2) {
#pragma unroll
    for (int p2 = 0; p2 < 4; ++p2) st16((wk - 2) * 4 + p2, acc[1][p2]);
  }
  __syncthreads();
  if (wk < 2) {
#pragma unroll
    for (int p2 = 0; p2 < 4; ++p2) ld16add(wk * 4 + p2, acc[1][p2]);
  }
  __syncthreads();
  if (wk == 1) {
#pragma unroll
    for (int p2 = 0; p2 < 4; ++p2) { st16(p2, acc[0][p2]); st16(4 + p2, acc[1][p2]); }
  }
  __syncthreads();
  if (wk == 0) {
#pragma unroll
    for (int p2 = 0; p2 < 4; ++p2) { ld16add(p2, acc[0][p2]); ld16add(4 + p2, acc[1][p2]); }
    // Store 64n x 128pix. D layout: col=l31, row=(reg&3)+8*(reg>>2)+4*half.
#pragma unroll
    for (int mt = 0; mt < 2; ++mt) {
#pragma unroll
      for (int reg = 0; reg < 16; ++reg) {
        int n = nq * 64 + mt * 32 + (reg & 3) + 8 * (reg >> 2) + 4 * half;
        float bv = biasout[n];
#pragma unroll
        for (int p2 = 0; p2 < 4; ++p2)
          out[((b * 256 + n) * 32 + h0 + p2) * 32 + l31] = acc[mt][p2][reg] + bv;
      }
    }
  }
}

// ---------------------------------------------------------------------------
extern "C" void kernel_launch(void* const* d_in, const int* in_sizes, int n_in,
                              void* d_out, int out_size, void* d_ws, size_t ws_size,
                              hipStream_t stream) {
  const float* x    = (const float*)d_in[0];
  const float* tw1  = (const float*)d_in[1];
  const float* tw2  = (const float*)d_in[2];
  const float* bias = (const float*)d_in[3];
  float* out = (float*)d_out;

  char* ws = (char*)d_ws;
  __hip_bfloat16* xTg = (__hip_bfloat16*)ws;
  __hip_bfloat16* Wg  = (__hip_bfloat16*)(ws + XT_BYTES);
  float* biasout      = (float*)(ws + XT_BYTES + WG_BYTES);

  k_prep<<<657, 256, 0, stream>>>(x, tw1, tw2, bias, xTg, Wg, biasout);
  k_gemm<<<512, 256, 0, stream>>>(xTg, Wg, biasout, out);
}